// Round 5
// baseline (72.131 us; speedup 1.0000x reference)
//
#include <hip/hip_runtime.h>
#include <math.h>

#define NCLUST 32
#define NPTS   1000000
#define LOG2E  1.4426950408889634f
#define TWO_PI 6.2831853071795864f
#define NBLOCKS 1024
#define SLOT_BASE 64   // ws slot offset (in unsigned words) for per-block partials

// Session ledger:
//  R3/R4: contended RMWs +17us; release/acquire (wbl2/inv) +10us -> RELAXED
//         agent-scope atomics + bit31 self-validation (poison has bit31 set;
//         partials are sums of squares, bit31 clear).
//  R5 (74.1): single kernel, 4 pts/thread, bare launch_bounds(256).
//  R6 (109):  launch_bounds(256,4) -> ILP loss. Counters: VALUBusy 12%,
//             FETCH 55.7MB (poll sweeps), kernel tail-bound. Reverted.
//  R7 (76.0): two-kernel split — wash (poll overlaps stragglers; extra
//             dispatch gap ~2us). Reverted.
//  R8 (72.0, best): X loads hoisted above __syncthreads + s_sleep(8) poll
//             throttle. Kernel now ~14.5us (total - 40.5 fill - ~17 harness).
//  R9 (this round): packed FP32. Pair point streams (A,B) and (C,D) as
//     float2 ext-vectors so arg chains + setup + acc emit v_pk_fma_f32
//     (VOP3P, 2 FMAs/instr on CDNA4). Per-thread VALU ~768 -> ~460 instrs.
//     exp2 remains scalar (no packed transcendental). Constants splat from
//     LDS float4 via op_sel. fp-contract=fast fuses mul+add into pk-fma.

typedef float v2f __attribute__((ext_vector_type(2)));

__device__ inline v2f splat2(float x) { v2f v; v.x = x; v.y = x; return v; }

__device__ inline void cluster_consts(int t,
                                      const float* __restrict__ means,
                                      const float* __restrict__ chols,
                                      const float* __restrict__ weights,
                                      float& a, float& b, float& c,
                                      float& e, float& f, float& W,
                                      float& L00, float& L10, float& L11,
                                      float& m0, float& m1, float& w) {
    float c00 = chols[t * 4 + 0];
    float c10 = chols[t * 4 + 2];
    float c11 = chols[t * 4 + 3];
    float S00 = fmaf(c00, c00, 1.0f);
    float S10 = c00 * c10;
    float S11 = c10 * c10 + c11 * c11 + 1.0f;
    L00 = sqrtf(S00);
    L10 = S10 / L00;
    L11 = sqrtf(S11 - L10 * L10);
    m0 = means[t * 2 + 0];
    m1 = means[t * 2 + 1];
    w  = weights[t];
    float iL00 = 1.0f / L00;
    float iL11 = 1.0f / L11;
    float Li00 = iL00;
    float Li10 = -L10 * iL00 * iL11;
    float Li11 = iL11;
    const float s = -0.5f * LOG2E;
    a = s * Li00; b = s * Li10; c = s * Li11;
    e = -(2.0f * a * m0 + b * m1);
    f = -(b * m0 + 2.0f * c * m1);
    float g = a * m0 * m0 + b * m0 * m1 + c * m1 * m1;
    float invnorm = 1.0f / (TWO_PI * sqrtf(L00 * L11));
    W = w * invnorm * exp2f(g);
}

__global__ __launch_bounds__(256) void nmsq_fused(const float* __restrict__ X,
                                                  const float* __restrict__ means,
                                                  const float* __restrict__ chols,
                                                  const float* __restrict__ weights,
                                                  unsigned* __restrict__ wsu,
                                                  float* __restrict__ out) {
    __shared__ float4 cc[NCLUST * 2];
    __shared__ float sL00[NCLUST], sL10[NCLUST], sL11[NCLUST];
    __shared__ float sM0[NCLUST], sM1[NCLUST], sW[NCLUST];
    __shared__ float red[4], redZ[4], redS[4];
    const int t = threadIdx.x;

    // ---- issue X loads FIRST: no LDS dependence, hide HBM latency ----
    const float4* X4 = (const float4*)X;     // 2 points per float4
    const int NV2 = NPTS / 4;                // 250000; thread handles X4[i], X4[i+NV2]
    const int i = blockIdx.x * blockDim.x + t;
    const bool active = (i < NV2);
    float4 p = make_float4(0.f, 0.f, 0.f, 0.f);
    float4 r = make_float4(0.f, 0.f, 0.f, 0.f);
    if (active) {
        p = X4[i];                           // points A (p.x,p.y), B (p.z,p.w)
        r = X4[i + NV2];                     // points C (r.x,r.y), D (r.z,r.w)
    }

    if (t < NCLUST) {
        float a, b, c, e, f, W, L00, L10, L11, m0, m1, w;
        cluster_consts(t, means, chols, weights, a, b, c, e, f, W,
                       L00, L10, L11, m0, m1, w);
        cc[2 * t]     = make_float4(a, b, c, e);
        cc[2 * t + 1] = make_float4(f, W, 0.0f, 0.0f);
        sL00[t] = L00; sL10[t] = L10; sL11[t] = L11;
        sM0[t] = m0;   sM1[t] = m1;   sW[t] = w;
    }
    __syncthreads();

    float acc = 0.0f;
    if (active) {
        // pack streams: AB lanes = (point A, point B), CD lanes = (C, D)
        v2f pxAB; pxAB.x = p.x; pxAB.y = p.z;
        v2f pyAB; pyAB.x = p.y; pyAB.y = p.w;
        v2f pxCD; pxCD.x = r.x; pxCD.y = r.z;
        v2f pyCD; pyCD.x = r.y; pyCD.y = r.w;
        v2f xxAB = pxAB * pxAB, xyAB = pxAB * pyAB, yyAB = pyAB * pyAB;
        v2f xxCD = pxCD * pxCD, xyCD = pxCD * pyCD, yyCD = pyCD * pyCD;
        v2f sAB = splat2(0.0f), sCD = splat2(0.0f);
        #pragma unroll
        for (int k = 0; k < NCLUST; ++k) {
            float4 c0 = cc[2 * k];
            float4 c1 = cc[2 * k + 1];
            v2f ax = splat2(c0.x), ay = splat2(c0.y), az = splat2(c0.z);
            v2f aw = splat2(c0.w), bx = splat2(c1.x), Wv = splat2(c1.y);
            // mul+add chains; -ffp-contract=fast fuses into v_pk_fma_f32
            v2f argAB = ax * xxAB + (ay * xyAB + (az * yyAB + (aw * pxAB + bx * pyAB)));
            v2f argCD = ax * xxCD + (ay * xyCD + (az * yyCD + (aw * pxCD + bx * pyCD)));
            v2f eAB, eCD;
            eAB.x = __builtin_amdgcn_exp2f(argAB.x);
            eAB.y = __builtin_amdgcn_exp2f(argAB.y);
            eCD.x = __builtin_amdgcn_exp2f(argCD.x);
            eCD.y = __builtin_amdgcn_exp2f(argCD.y);
            sAB = Wv * eAB + sAB;
            sCD = Wv * eCD + sCD;
        }
        acc = fmaf(sAB.x, sAB.x, fmaf(sAB.y, sAB.y,
              fmaf(sCD.x, sCD.x, sCD.y * sCD.y)));
    }

    #pragma unroll
    for (int off = 32; off > 0; off >>= 1) acc += __shfl_down(acc, off, 64);
    int lane = t & 63, wid = t >> 6;
    if (lane == 0) red[wid] = acc;
    __syncthreads();

    if (t == 0) {
        float partial = red[0] + red[1] + red[2] + red[3];  // >= 0, bit31 == 0
        __hip_atomic_store(&wsu[SLOT_BASE + blockIdx.x], __float_as_uint(partial),
                           __ATOMIC_RELAXED, __HIP_MEMORY_SCOPE_AGENT);
    }
    if (blockIdx.x != 0) return;

    // ---- block 0 only: Z over 1024 (i,j) pairs (overlaps straggler tails) ----
    float zp = 0.0f;
    for (int q = t; q < NCLUST * NCLUST; q += 256) {
        int ii = q >> 5, jj = q & 31;
        float A = sL00[ii] + sL00[jj];
        float B = sL10[ii] + sL10[jj];
        float C = sL11[ii] + sL11[jj];
        float d0 = sM0[ii] - sM0[jj];
        float d1 = sM1[ii] - sM1[jj];
        float iA = 1.0f / A, iC = 1.0f / C;
        float qz = d0 * d0 * iA + d1 * d1 * iC - B * d0 * d1 * iA * iC;
        float zt = __builtin_amdgcn_exp2f(-0.5f * LOG2E * qz) / (TWO_PI * sqrtf(A * C));
        zp = fmaf(zt * sW[ii], sW[jj], zp);
    }
    #pragma unroll
    for (int off = 32; off > 0; off >>= 1) zp += __shfl_down(zp, off, 64);
    if (lane == 0) redZ[wid] = zp;

    // ---- poll all 1024 partial slots: 4 pipelined loads per sweep, ----
    // ---- s_sleep(8) (~512cy) between sweeps to cut coherence traffic ----
    unsigned v0, v1, v2, v3;
    for (;;) {
        v0 = __hip_atomic_load(&wsu[SLOT_BASE + t + 0 * 256],
                               __ATOMIC_RELAXED, __HIP_MEMORY_SCOPE_AGENT);
        v1 = __hip_atomic_load(&wsu[SLOT_BASE + t + 1 * 256],
                               __ATOMIC_RELAXED, __HIP_MEMORY_SCOPE_AGENT);
        v2 = __hip_atomic_load(&wsu[SLOT_BASE + t + 2 * 256],
                               __ATOMIC_RELAXED, __HIP_MEMORY_SCOPE_AGENT);
        v3 = __hip_atomic_load(&wsu[SLOT_BASE + t + 3 * 256],
                               __ATOMIC_RELAXED, __HIP_MEMORY_SCOPE_AGENT);
        if (!((v0 | v1 | v2 | v3) & 0x80000000u)) break;   // all bit31 clear
        __builtin_amdgcn_s_sleep(8);
    }
    float sp = __uint_as_float(v0) + __uint_as_float(v1) +
               __uint_as_float(v2) + __uint_as_float(v3);
    #pragma unroll
    for (int off = 32; off > 0; off >>= 1) sp += __shfl_down(sp, off, 64);
    if (lane == 0) redS[wid] = sp;
    __syncthreads();

    if (t == 0) {
        float Z = redZ[0] + redZ[1] + redZ[2] + redZ[3];
        float S = redS[0] + redS[1] + redS[2] + redS[3];
        out[0] = (logf(Z) - logf(S)) * (1.0f / (float)NPTS);
    }
}

extern "C" void kernel_launch(void* const* d_in, const int* in_sizes, int n_in,
                              void* d_out, int out_size, void* d_ws, size_t ws_size,
                              hipStream_t stream) {
    const float* X       = (const float*)d_in[0];
    const float* means   = (const float*)d_in[1];
    const float* chols   = (const float*)d_in[2];
    const float* weights = (const float*)d_in[3];
    // d_in[4] = it (unused)
    unsigned* wsu = (unsigned*)d_ws;
    float* out = (float*)d_out;

    nmsq_fused<<<NBLOCKS, 256, 0, stream>>>(X, means, chols, weights, wsu, out);
}

// Round 6
// 72.107 us; speedup vs baseline: 1.0003x; 1.0003x over previous
//
#include <hip/hip_runtime.h>
#include <math.h>

#define NCLUST 32
#define NPTS   1000000
#define LOG2E  1.4426950408889634f
#define TWO_PI 6.2831853071795864f
#define NBLOCKS 1024
#define SLOT_BASE 64   // ws slot offset (in unsigned words) for per-block partials

// Session ledger:
//  R3/R4: contended RMWs +17us; release/acquire (wbl2/inv) +10us -> RELAXED
//         agent-scope atomics + bit31 self-validation (poison has bit31 set;
//         partials are sums of squares, bit31 clear).
//  R5 (74.1): single kernel, 4 pts/thread. R6 (109): (256,4) regression.
//  R7 (76.0): two-kernel split — wash. Budget: fixed harness ~58.2us
//         (fill 40.5 + reset gaps 17.7) + kernel ~13.8us.
//  R8 (72.0): X-load hoist above barrier + s_sleep(8) poll throttle.
//  R9 (72.1): packed v_pk_fma_f32 — NEUTRAL. Second neutral arithmetic opt
//         (after R5) => kernel is NOT VALU-issue-bound.
//  H1': kernel window carries ~103.5MB of background WRITE_SIZE (poison
//         drain from L2/L3; we write 4KB). 103+9 MB at ~8TB/s fabric = ~14us
//         = measured kernel duration. Kernel is drain-limited.
//  R10 (this round): X loads made NON-TEMPORAL (no L2 allocate). Theory:
//         normal loads force synchronous eviction of dirty poison lines from
//         L2 (~up to 32MB) in our critical path; nt loads leave them to
//         drain lazily. X is read once — no reuse lost. If neutral, the
//         drain is pure background and the kernel is at its roofline.

typedef float v2f __attribute__((ext_vector_type(2)));
typedef float v4f __attribute__((ext_vector_type(4)));

__device__ inline v2f splat2(float x) { v2f v; v.x = x; v.y = x; return v; }

__device__ inline void cluster_consts(int t,
                                      const float* __restrict__ means,
                                      const float* __restrict__ chols,
                                      const float* __restrict__ weights,
                                      float& a, float& b, float& c,
                                      float& e, float& f, float& W,
                                      float& L00, float& L10, float& L11,
                                      float& m0, float& m1, float& w) {
    float c00 = chols[t * 4 + 0];
    float c10 = chols[t * 4 + 2];
    float c11 = chols[t * 4 + 3];
    float S00 = fmaf(c00, c00, 1.0f);
    float S10 = c00 * c10;
    float S11 = c10 * c10 + c11 * c11 + 1.0f;
    L00 = sqrtf(S00);
    L10 = S10 / L00;
    L11 = sqrtf(S11 - L10 * L10);
    m0 = means[t * 2 + 0];
    m1 = means[t * 2 + 1];
    w  = weights[t];
    float iL00 = 1.0f / L00;
    float iL11 = 1.0f / L11;
    float Li00 = iL00;
    float Li10 = -L10 * iL00 * iL11;
    float Li11 = iL11;
    const float s = -0.5f * LOG2E;
    a = s * Li00; b = s * Li10; c = s * Li11;
    e = -(2.0f * a * m0 + b * m1);
    f = -(b * m0 + 2.0f * c * m1);
    float g = a * m0 * m0 + b * m0 * m1 + c * m1 * m1;
    float invnorm = 1.0f / (TWO_PI * sqrtf(L00 * L11));
    W = w * invnorm * exp2f(g);
}

__global__ __launch_bounds__(256) void nmsq_fused(const float* __restrict__ X,
                                                  const float* __restrict__ means,
                                                  const float* __restrict__ chols,
                                                  const float* __restrict__ weights,
                                                  unsigned* __restrict__ wsu,
                                                  float* __restrict__ out) {
    __shared__ float4 cc[NCLUST * 2];
    __shared__ float sL00[NCLUST], sL10[NCLUST], sL11[NCLUST];
    __shared__ float sM0[NCLUST], sM1[NCLUST], sW[NCLUST];
    __shared__ float red[4], redZ[4], redS[4];
    const int t = threadIdx.x;

    // ---- issue X loads FIRST (non-temporal: no L2 allocate, no forced ----
    // ---- eviction of dirty poison lines; X is read exactly once)      ----
    const v4f* X4 = (const v4f*)X;           // 2 points per float4
    const int NV2 = NPTS / 4;                // 250000; thread handles X4[i], X4[i+NV2]
    const int i = blockIdx.x * blockDim.x + t;
    const bool active = (i < NV2);
    v4f p = (v4f)(0.0f);
    v4f r = (v4f)(0.0f);
    if (active) {
        p = __builtin_nontemporal_load(X4 + i);        // A (p.x,p.y), B (p.z,p.w)
        r = __builtin_nontemporal_load(X4 + i + NV2);  // C (r.x,r.y), D (r.z,r.w)
    }

    if (t < NCLUST) {
        float a, b, c, e, f, W, L00, L10, L11, m0, m1, w;
        cluster_consts(t, means, chols, weights, a, b, c, e, f, W,
                       L00, L10, L11, m0, m1, w);
        cc[2 * t]     = make_float4(a, b, c, e);
        cc[2 * t + 1] = make_float4(f, W, 0.0f, 0.0f);
        sL00[t] = L00; sL10[t] = L10; sL11[t] = L11;
        sM0[t] = m0;   sM1[t] = m1;   sW[t] = w;
    }
    __syncthreads();

    float acc = 0.0f;
    if (active) {
        // pack streams: AB lanes = (point A, point B), CD lanes = (C, D)
        v2f pxAB; pxAB.x = p.x; pxAB.y = p.z;
        v2f pyAB; pyAB.x = p.y; pyAB.y = p.w;
        v2f pxCD; pxCD.x = r.x; pxCD.y = r.z;
        v2f pyCD; pyCD.x = r.y; pyCD.y = r.w;
        v2f xxAB = pxAB * pxAB, xyAB = pxAB * pyAB, yyAB = pyAB * pyAB;
        v2f xxCD = pxCD * pxCD, xyCD = pxCD * pyCD, yyCD = pyCD * pyCD;
        v2f sAB = splat2(0.0f), sCD = splat2(0.0f);
        #pragma unroll
        for (int k = 0; k < NCLUST; ++k) {
            float4 c0 = cc[2 * k];
            float4 c1 = cc[2 * k + 1];
            v2f ax = splat2(c0.x), ay = splat2(c0.y), az = splat2(c0.z);
            v2f aw = splat2(c0.w), bx = splat2(c1.x), Wv = splat2(c1.y);
            v2f argAB = ax * xxAB + (ay * xyAB + (az * yyAB + (aw * pxAB + bx * pyAB)));
            v2f argCD = ax * xxCD + (ay * xyCD + (az * yyCD + (aw * pxCD + bx * pyCD)));
            v2f eAB, eCD;
            eAB.x = __builtin_amdgcn_exp2f(argAB.x);
            eAB.y = __builtin_amdgcn_exp2f(argAB.y);
            eCD.x = __builtin_amdgcn_exp2f(argCD.x);
            eCD.y = __builtin_amdgcn_exp2f(argCD.y);
            sAB = Wv * eAB + sAB;
            sCD = Wv * eCD + sCD;
        }
        acc = fmaf(sAB.x, sAB.x, fmaf(sAB.y, sAB.y,
              fmaf(sCD.x, sCD.x, sCD.y * sCD.y)));
    }

    #pragma unroll
    for (int off = 32; off > 0; off >>= 1) acc += __shfl_down(acc, off, 64);
    int lane = t & 63, wid = t >> 6;
    if (lane == 0) red[wid] = acc;
    __syncthreads();

    if (t == 0) {
        float partial = red[0] + red[1] + red[2] + red[3];  // >= 0, bit31 == 0
        __hip_atomic_store(&wsu[SLOT_BASE + blockIdx.x], __float_as_uint(partial),
                           __ATOMIC_RELAXED, __HIP_MEMORY_SCOPE_AGENT);
    }
    if (blockIdx.x != 0) return;

    // ---- block 0 only: Z over 1024 (i,j) pairs (overlaps straggler tails) ----
    float zp = 0.0f;
    for (int q = t; q < NCLUST * NCLUST; q += 256) {
        int ii = q >> 5, jj = q & 31;
        float A = sL00[ii] + sL00[jj];
        float B = sL10[ii] + sL10[jj];
        float C = sL11[ii] + sL11[jj];
        float d0 = sM0[ii] - sM0[jj];
        float d1 = sM1[ii] - sM1[jj];
        float iA = 1.0f / A, iC = 1.0f / C;
        float qz = d0 * d0 * iA + d1 * d1 * iC - B * d0 * d1 * iA * iC;
        float zt = __builtin_amdgcn_exp2f(-0.5f * LOG2E * qz) / (TWO_PI * sqrtf(A * C));
        zp = fmaf(zt * sW[ii], sW[jj], zp);
    }
    #pragma unroll
    for (int off = 32; off > 0; off >>= 1) zp += __shfl_down(zp, off, 64);
    if (lane == 0) redZ[wid] = zp;

    // ---- poll all 1024 partial slots: 4 pipelined loads per sweep, ----
    // ---- s_sleep(8) (~512cy) between sweeps to cut coherence traffic ----
    unsigned v0, v1, v2, v3;
    for (;;) {
        v0 = __hip_atomic_load(&wsu[SLOT_BASE + t + 0 * 256],
                               __ATOMIC_RELAXED, __HIP_MEMORY_SCOPE_AGENT);
        v1 = __hip_atomic_load(&wsu[SLOT_BASE + t + 1 * 256],
                               __ATOMIC_RELAXED, __HIP_MEMORY_SCOPE_AGENT);
        v2 = __hip_atomic_load(&wsu[SLOT_BASE + t + 2 * 256],
                               __ATOMIC_RELAXED, __HIP_MEMORY_SCOPE_AGENT);
        v3 = __hip_atomic_load(&wsu[SLOT_BASE + t + 3 * 256],
                               __ATOMIC_RELAXED, __HIP_MEMORY_SCOPE_AGENT);
        if (!((v0 | v1 | v2 | v3) & 0x80000000u)) break;   // all bit31 clear
        __builtin_amdgcn_s_sleep(8);
    }
    float sp = __uint_as_float(v0) + __uint_as_float(v1) +
               __uint_as_float(v2) + __uint_as_float(v3);
    #pragma unroll
    for (int off = 32; off > 0; off >>= 1) sp += __shfl_down(sp, off, 64);
    if (lane == 0) redS[wid] = sp;
    __syncthreads();

    if (t == 0) {
        float Z = redZ[0] + redZ[1] + redZ[2] + redZ[3];
        float S = redS[0] + redS[1] + redS[2] + redS[3];
        out[0] = (logf(Z) - logf(S)) * (1.0f / (float)NPTS);
    }
}

extern "C" void kernel_launch(void* const* d_in, const int* in_sizes, int n_in,
                              void* d_out, int out_size, void* d_ws, size_t ws_size,
                              hipStream_t stream) {
    const float* X       = (const float*)d_in[0];
    const float* means   = (const float*)d_in[1];
    const float* chols   = (const float*)d_in[2];
    const float* weights = (const float*)d_in[3];
    // d_in[4] = it (unused)
    unsigned* wsu = (unsigned*)d_ws;
    float* out = (float*)d_out;

    nmsq_fused<<<NBLOCKS, 256, 0, stream>>>(X, means, chols, weights, wsu, out);
}